// Round 3
// baseline (734.740 us; speedup 1.0000x reference)
//
#include <hip/hip_runtime.h>
#include <hip/hip_bf16.h>
#include <math.h>

typedef __bf16 bf16;
typedef __bf16 bf16x8 __attribute__((ext_vector_type(8)));
typedef float f32x4 __attribute__((ext_vector_type(4)));

#define N_ENT   100000
#define N_REL   16
#define N_EDGES 1600000
#define E_PAD   (N_EDGES + 256)   // bucket records padded (<=16 pad slots per relation)
#define OUT_STRIDE 160
#define NCHUNK  98   // ceil(N_ENT/1024)

// ---------- fill an int region (grid-stride) ----------
__global__ __launch_bounds__(256) void fill_kernel(int* __restrict__ p, int v, int n) {
    int i = blockIdx.x * 256 + threadIdx.x;
    int stride = gridDim.x * 256;
    for (; i < n; i += stride) p[i] = v;
}

// ---------- ws-too-small tripwire ----------
__global__ __launch_bounds__(256) void zero_out_kernel(float* __restrict__ out, int n) {
    int i = blockIdx.x * 256 + threadIdx.x;
    int stride = gridDim.x * 256;
    for (; i < n; i += stride) out[i] = 0.f;
}

// ---------- ent (fp32) -> entb (bf16); also builds W0^T / W1^T bf16 hi/lo tables ----------
__global__ __launch_bounds__(256) void ent2b_kernel(const float* __restrict__ ent, bf16* __restrict__ entb,
                                                    const float* __restrict__ W0, const float* __restrict__ W1,
                                                    bf16* __restrict__ W0Th, bf16* __restrict__ W0Tl,
                                                    bf16* __restrict__ W1Th, bf16* __restrict__ W1Tl) {
    int id = blockIdx.x * 256 + threadIdx.x;
    if (id < 4096) {                 // W0 is [64][64] row-major: W0[k*64+n] -> W0T[n][k]
        int k = id >> 6, n = id & 63;
        float v = W0[id];
        bf16 h = (bf16)v;
        W0Th[n * 64 + k] = h;
        W0Tl[n * 64 + k] = (bf16)(v - (float)h);
        if (id < 2048) {             // W1 is [64][32]: W1[k*32+n] -> W1T[n][k]
            int k1 = id >> 5, n1 = id & 31;
            float v1 = W1[id];
            bf16 h1 = (bf16)v1;
            W1Th[n1 * 64 + k1] = h1;
            W1Tl[n1 * 64 + k1] = (bf16)(v1 - (float)h1);
        }
    }
    int i = id * 4;
    int stride = gridDim.x * 1024;
    for (; i < N_ENT * 64; i += stride) {
        float4 v = *(const float4*)(ent + i);
        entb[i]     = (bf16)v.x;
        entb[i + 1] = (bf16)v.y;
        entb[i + 2] = (bf16)v.z;
        entb[i + 3] = (bf16)v.w;
    }
}

// ---------- etype histogram (LDS-staged) ----------
__global__ __launch_bounds__(256) void hist16_kernel(const int* __restrict__ ety, int* __restrict__ cnt16) {
    __shared__ int h16[16];
    int t = threadIdx.x;
    if (t < 16) h16[t] = 0;
    __syncthreads();
    int e = blockIdx.x * 256 + t;
    if (e < N_EDGES) atomicAdd(&h16[ety[e]], 1);
    __syncthreads();
    if (t < 16 && h16[t] > 0) atomicAdd(&cnt16[t], h16[t]);
}

// padded bucket offsets (each bucket start multiple of 16)
__global__ void bucket_scan(const int* __restrict__ cnt16, int* __restrict__ bptr16, int* __restrict__ cur16) {
    if (threadIdx.x == 0) {
        int s = 0;
        for (int r = 0; r < N_REL; ++r) {
            bptr16[r] = s; cur16[r] = s;
            s += (cnt16[r] + 15) & ~15;
        }
        bptr16[N_REL] = s;
    }
}

// set dst=-1 sentinel on the <=16 pad slots at the tail of each relation bucket
__global__ void pad_fill(const int* __restrict__ cnt16, const int* __restrict__ bptr16, int4* __restrict__ bedge) {
    int t = threadIdx.x;           // 256 threads: r = t>>4, i = t&15
    int r = t >> 4, i = t & 15;
    int idx = bptr16[r] + cnt16[r] + i;
    if (idx < bptr16[r + 1]) bedge[idx] = make_int4(0, -1, 0, 0);
}

// ballot-rank scatter into padded etype buckets; record = {src, dst, within-dst rank, 0}
__global__ __launch_bounds__(256) void bucket_scatter(const int* __restrict__ src, const int* __restrict__ dst,
                                                      const int* __restrict__ ety, int* __restrict__ cur16,
                                                      int4* __restrict__ bedge, int* __restrict__ cnt) {
    __shared__ int whist[4][16];
    __shared__ int wbase[4][16];
    __shared__ int bbase[16];
    int t = threadIdx.x, wave = t >> 6, lane = t & 63;
    int e = blockIdx.x * 256 + t;
    int b = -1, d = 0, nrank = 0;
    if (e < N_EDGES) {
        b = ety[e];
        d = dst[e];
        nrank = atomicAdd(&cnt[d], 1);
    }
    unsigned long long ltmask = (1ull << lane) - 1ull;
    int brk = 0;
#pragma unroll
    for (int r = 0; r < 16; ++r) {
        unsigned long long mk = __ballot(b == r);
        if (b == r) brk = __popcll(mk & ltmask);
        if (lane == r) whist[wave][r] = __popcll(mk);
    }
    __syncthreads();
    if (t < 16) {
        int s0 = whist[0][t], s1 = whist[1][t], s2 = whist[2][t], s3 = whist[3][t];
        bbase[t] = atomicAdd(&cur16[t], s0 + s1 + s2 + s3);
        wbase[0][t] = 0; wbase[1][t] = s0; wbase[2][t] = s0 + s1; wbase[3][t] = s0 + s1 + s2;
    }
    __syncthreads();
    if (b >= 0) {
        int pos = bbase[b] + wbase[wave][b] + brk;
        bedge[pos] = make_int4(src[e], d, nrank, 0);
    }
}

// ---------- dst-CSR scans ----------
__global__ __launch_bounds__(256) void scan1(const int* __restrict__ cnt, int* __restrict__ part) {
    __shared__ int sh[256];
    int bIdx = blockIdx.x, t = threadIdx.x;
    int i0 = bIdx * 1024 + t * 4;
    int s = 0;
#pragma unroll
    for (int u = 0; u < 4; ++u) { int i = i0 + u; if (i < N_ENT) s += cnt[i]; }
    sh[t] = s; __syncthreads();
    for (int o = 128; o > 0; o >>= 1) { if (t < o) sh[t] += sh[t + o]; __syncthreads(); }
    if (t == 0) part[bIdx] = sh[0];
}

__global__ void scan2(const int* __restrict__ part, int* __restrict__ pbase) {
    if (threadIdx.x == 0) {
        int s = 0;
        for (int i = 0; i < NCHUNK; ++i) { pbase[i] = s; s += part[i]; }
    }
}

__global__ __launch_bounds__(256) void scan3(const int* __restrict__ cnt, const int* __restrict__ pbase,
                                             int* __restrict__ row_ptr) {
    __shared__ int sh[256];
    int bIdx = blockIdx.x, t = threadIdx.x;
    int i0 = bIdx * 1024 + t * 4;
    int c[4]; int s = 0;
#pragma unroll
    for (int u = 0; u < 4; ++u) { c[u] = (i0 + u < N_ENT) ? cnt[i0 + u] : 0; s += c[u]; }
    sh[t] = s; __syncthreads();
    for (int o = 1; o < 256; o <<= 1) {
        int add = (t >= o) ? sh[t - o] : 0;
        __syncthreads();
        sh[t] += add;
        __syncthreads();
    }
    int run = pbase[bIdx] + sh[t] - s;
#pragma unroll
    for (int u = 0; u < 4; ++u) {
        if (i0 + u < N_ENT) { row_ptr[i0 + u] = run; run += c[u]; }
    }
    if (bIdx == 0 && t == 0) row_ptr[N_ENT] = N_EDGES;
}

// ---------- fused per-edge MFMA attention ----------
// Writes pair[rowp[d]+rank] = {src, exp(att)} and atomically accumulates denom[d] += exp(att).
// No max-subtraction needed: |att| is O(1) for this data scale (0.1-scale embeddings), exp is safe.
__global__ __launch_bounds__(256) void fused_att(const bf16* __restrict__ entb, const float* __restrict__ W_R,
                                                 const float* __restrict__ rel, const int4* __restrict__ bedge,
                                                 const int* __restrict__ bptr16, const int* __restrict__ rowp,
                                                 int2* __restrict__ pair, float* __restrict__ denom) {
    __shared__ bf16 WT[64 * 72];     // WT[n][k] = W_r[k][n]
    __shared__ float relS[64];
    const int r = blockIdx.y;
    const int t = threadIdx.x;
    const float* Wr = W_R + (size_t)r * 4096;
    for (int idx = t; idx < 4096; idx += 256) {
        int k = idx >> 6, n = idx & 63;
        WT[n * 72 + k] = (bf16)Wr[idx];
    }
    if (t < 64) relS[t] = rel[r * 64 + t];
    __syncthreads();

    const int lane = t & 63, m = lane & 15, q = lane >> 4;
    bf16x8 bb[4][2];
#pragma unroll
    for (int nt = 0; nt < 4; ++nt)
#pragma unroll
        for (int ks = 0; ks < 2; ++ks)
            bb[nt][ks] = *(const bf16x8*)&WT[(nt * 16 + m) * 72 + ks * 32 + q * 8];

    int g0 = bptr16[r] >> 4, g1 = bptr16[r + 1] >> 4;
    int wv = blockIdx.x * 4 + (t >> 6);
    int nw = gridDim.x * 4;
    for (int g = g0 + wv; g < g1; g += nw) {
        int4 be = bedge[g * 16 + m];
        int sidx = be.x < 0 ? 0 : be.x;      // pad slots clamped for the gather
        int didx = be.y < 0 ? 0 : be.y;
        const bf16* sp = entb + (size_t)sidx * 64;
        const bf16* dp = entb + (size_t)didx * 64;
        bf16x8 as0 = *(const bf16x8*)(sp + q * 8);
        bf16x8 as1 = *(const bf16x8*)(sp + 32 + q * 8);
        bf16x8 ad0 = *(const bf16x8*)(dp + q * 8);
        bf16x8 ad1 = *(const bf16x8*)(dp + 32 + q * 8);
        float part0 = 0.f, part1 = 0.f, part2 = 0.f, part3 = 0.f;
#pragma unroll
        for (int nt = 0; nt < 4; ++nt) {
            f32x4 tacc = {0.f, 0.f, 0.f, 0.f};
            tacc = __builtin_amdgcn_mfma_f32_16x16x32_bf16(as0, bb[nt][0], tacc, 0, 0, 0);
            tacc = __builtin_amdgcn_mfma_f32_16x16x32_bf16(as1, bb[nt][1], tacc, 0, 0, 0);
            f32x4 hacc = {0.f, 0.f, 0.f, 0.f};
            hacc = __builtin_amdgcn_mfma_f32_16x16x32_bf16(ad0, bb[nt][0], hacc, 0, 0, 0);
            hacc = __builtin_amdgcn_mfma_f32_16x16x32_bf16(ad1, bb[nt][1], hacc, 0, 0, 0);
            float rl = relS[nt * 16 + m];
#pragma unroll
            for (int i = 0; i < 4; ++i) {
                float z = hacc[i] + rl;
                float ez = __expf(2.f * z);                 // tanh(z) = 1 - 2/(e^{2z}+1)
                float th = 1.f - 2.f / (ez + 1.f);
                float tv = tacc[i] * th;
                if (i == 0) part0 += tv; else if (i == 1) part1 += tv;
                else if (i == 2) part2 += tv; else part3 += tv;
            }
        }
#pragma unroll
        for (int o = 1; o < 16; o <<= 1) {    // reduce over dim-lanes; xor<16 stays in edge group
            part0 += __shfl_xor(part0, o);
            part1 += __shfl_xor(part1, o);
            part2 += __shfl_xor(part2, o);
            part3 += __shfl_xor(part3, o);
        }
        if (m == 0) {
            float v[4] = {part0, part1, part2, part3};
#pragma unroll
            for (int i = 0; i < 4; ++i) {
                int4 w = bedge[g * 16 + q * 4 + i];          // L1-hot reread
                if (w.y >= 0) {
                    float ev = __expf(v[i]);
                    int slot = rowp[w.y] + w.z;              // unique CSR slot, no atomic
                    pair[slot] = make_int2(w.x, __float_as_int(ev));
                    atomicAdd(&denom[w.y], ev);
                }
            }
        }
    }
}

// ---------- fused layer 1: CSR gather (pair.y = exp(att), scale by 1/denom) + MFMA transform1 ----------
// One wave per node, no barriers, no softmax passes, no exp: pure 8-wide-unrolled gather.
__global__ __launch_bounds__(256) void fused_layer1(const float* __restrict__ ent, const bf16* __restrict__ entb,
                                                    const bf16* __restrict__ W0Th, const bf16* __restrict__ W0Tl,
                                                    const int* __restrict__ rowp, const float* __restrict__ denom,
                                                    const int2* __restrict__ pair, bf16* __restrict__ h1b,
                                                    float* __restrict__ out) {
    __shared__ bf16 xsh[4][80];   // per-wave x hi strip
    __shared__ bf16 xsl[4][80];   // per-wave x lo strip
    int t = threadIdx.x;
    int w = t >> 6;
    int node = blockIdx.x * 4 + w;           // grid is exactly N_ENT/4
    int j = t & 63;
    int r0 = __builtin_amdgcn_readfirstlane(rowp[node]);
    int r1 = __builtin_amdgcn_readfirstlane(rowp[node + 1]);
    float h0v = ent[(size_t)node * 64 + j];  // issue early, consumed late
    float dn = denom[node];
    float inv = dn > 0.f ? 1.f / dn : 0.f;   // deg==0 -> acc stays 0

    float acc = 0.f;
    int k = r0;
    for (; k + 8 <= r1; k += 8) {
        int2 p0 = pair[k],     p1 = pair[k + 1], p2 = pair[k + 2], p3 = pair[k + 3];
        int2 p4 = pair[k + 4], p5 = pair[k + 5], p6 = pair[k + 6], p7 = pair[k + 7];
        float f0 = (float)entb[(size_t)p0.x * 64 + j];
        float f1 = (float)entb[(size_t)p1.x * 64 + j];
        float f2 = (float)entb[(size_t)p2.x * 64 + j];
        float f3 = (float)entb[(size_t)p3.x * 64 + j];
        float f4 = (float)entb[(size_t)p4.x * 64 + j];
        float f5 = (float)entb[(size_t)p5.x * 64 + j];
        float f6 = (float)entb[(size_t)p6.x * 64 + j];
        float f7 = (float)entb[(size_t)p7.x * 64 + j];
        acc += __int_as_float(p0.y) * f0; acc += __int_as_float(p1.y) * f1;
        acc += __int_as_float(p2.y) * f2; acc += __int_as_float(p3.y) * f3;
        acc += __int_as_float(p4.y) * f4; acc += __int_as_float(p5.y) * f5;
        acc += __int_as_float(p6.y) * f6; acc += __int_as_float(p7.y) * f7;
    }
    for (; k + 4 <= r1; k += 4) {
        int2 p0 = pair[k], p1 = pair[k + 1], p2 = pair[k + 2], p3 = pair[k + 3];
        float f0 = (float)entb[(size_t)p0.x * 64 + j];
        float f1 = (float)entb[(size_t)p1.x * 64 + j];
        float f2 = (float)entb[(size_t)p2.x * 64 + j];
        float f3 = (float)entb[(size_t)p3.x * 64 + j];
        acc += __int_as_float(p0.y) * f0; acc += __int_as_float(p1.y) * f1;
        acc += __int_as_float(p2.y) * f2; acc += __int_as_float(p3.y) * f3;
    }
    for (; k < r1; ++k) {
        int2 p = pair[k];
        acc += __int_as_float(p.y) * (float)entb[(size_t)p.x * 64 + j];
    }
    acc *= inv;

    // transform1: h1 = lrelu((h0 * agg) @ W0) via MFMA, bf16 hi/lo split (~fp32 accuracy)
    float x = h0v * acc;
    bf16 xh = (bf16)x;
    bf16 xl = (bf16)(x - (float)xh);
    xsh[w][j] = xh;
    xsl[w][j] = xl;
    // same-wave LDS RAW: compiler inserts lgkmcnt; no __syncthreads (waves independent)
    const int m16 = j & 15, q = j >> 4;
    bf16x8 ah0 = *(const bf16x8*)&xsh[w][q * 8];        // row-replicated A fragments
    bf16x8 ah1 = *(const bf16x8*)&xsh[w][32 + q * 8];
    bf16x8 al0 = *(const bf16x8*)&xsl[w][q * 8];
    bf16x8 al1 = *(const bf16x8*)&xsl[w][32 + q * 8];

    float cand0, cand1, cand2, cand3;
#pragma unroll
    for (int nt = 0; nt < 4; ++nt) {
        const bf16* bh = W0Th + (nt * 16 + m16) * 64;   // B[col=nt*16+m16][k]
        const bf16* bl = W0Tl + (nt * 16 + m16) * 64;
        bf16x8 bh0 = *(const bf16x8*)(bh + q * 8);
        bf16x8 bh1 = *(const bf16x8*)(bh + 32 + q * 8);
        bf16x8 bl0 = *(const bf16x8*)(bl + q * 8);
        bf16x8 bl1 = *(const bf16x8*)(bl + 32 + q * 8);
        f32x4 c = {0.f, 0.f, 0.f, 0.f};
        c = __builtin_amdgcn_mfma_f32_16x16x32_bf16(ah0, bh0, c, 0, 0, 0);
        c = __builtin_amdgcn_mfma_f32_16x16x32_bf16(ah1, bh1, c, 0, 0, 0);
        c = __builtin_amdgcn_mfma_f32_16x16x32_bf16(al0, bh0, c, 0, 0, 0);
        c = __builtin_amdgcn_mfma_f32_16x16x32_bf16(al1, bh1, c, 0, 0, 0);
        c = __builtin_amdgcn_mfma_f32_16x16x32_bf16(ah0, bl0, c, 0, 0, 0);
        c = __builtin_amdgcn_mfma_f32_16x16x32_bf16(ah1, bl1, c, 0, 0, 0);
        // all C rows identical (A rows replicated) -> c[0] = out[col=m16] of block nt
        float v = c[0];
        if (nt == 0) cand0 = v; else if (nt == 1) cand1 = v; else if (nt == 2) cand2 = v; else cand3 = v;
    }
    // lane j (= q*16 + m16) already holds outdim j in cand_q
    float a2 = (q == 0) ? cand0 : (q == 1) ? cand1 : (q == 2) ? cand2 : cand3;

    float h1v = a2 > 0.f ? a2 : 0.01f * a2;
    h1b[(size_t)node * 64 + j] = (bf16)h1v;
    float ss = h1v * h1v;
#pragma unroll
    for (int o = 1; o < 64; o <<= 1) ss += __shfl_xor(ss, o);
    float inv2 = 1.f / fmaxf(sqrtf(ss), 1e-12f);
    out[(size_t)node * OUT_STRIDE + j] = h0v;
    out[(size_t)node * OUT_STRIDE + 64 + j] = h1v * inv2;
}

// ---------- fused layer 2: CSR gather (h1b rows, weight = pair.y/denom) + MFMA transform2 ----------
__global__ __launch_bounds__(256) void fused_layer2(const bf16* __restrict__ h1b,
                                                    const bf16* __restrict__ W1Th, const bf16* __restrict__ W1Tl,
                                                    const int* __restrict__ rowp, const float* __restrict__ denom,
                                                    const int2* __restrict__ pair, float* __restrict__ out) {
    __shared__ bf16 xsh[4][80];
    __shared__ bf16 xsl[4][80];
    int t = threadIdx.x;
    int w = t >> 6;
    int node = blockIdx.x * 4 + w;
    int j = t & 63;
    int r0 = __builtin_amdgcn_readfirstlane(rowp[node]);
    int r1 = __builtin_amdgcn_readfirstlane(rowp[node + 1]);
    float dn = denom[node];
    float inv = dn > 0.f ? 1.f / dn : 0.f;

    float acc = 0.f;
    int k = r0;
    for (; k + 8 <= r1; k += 8) {
        int2 p0 = pair[k],     p1 = pair[k + 1], p2 = pair[k + 2], p3 = pair[k + 3];
        int2 p4 = pair[k + 4], p5 = pair[k + 5], p6 = pair[k + 6], p7 = pair[k + 7];
        float f0 = (float)h1b[(size_t)p0.x * 64 + j];
        float f1 = (float)h1b[(size_t)p1.x * 64 + j];
        float f2 = (float)h1b[(size_t)p2.x * 64 + j];
        float f3 = (float)h1b[(size_t)p3.x * 64 + j];
        float f4 = (float)h1b[(size_t)p4.x * 64 + j];
        float f5 = (float)h1b[(size_t)p5.x * 64 + j];
        float f6 = (float)h1b[(size_t)p6.x * 64 + j];
        float f7 = (float)h1b[(size_t)p7.x * 64 + j];
        acc += __int_as_float(p0.y) * f0; acc += __int_as_float(p1.y) * f1;
        acc += __int_as_float(p2.y) * f2; acc += __int_as_float(p3.y) * f3;
        acc += __int_as_float(p4.y) * f4; acc += __int_as_float(p5.y) * f5;
        acc += __int_as_float(p6.y) * f6; acc += __int_as_float(p7.y) * f7;
    }
    for (; k + 4 <= r1; k += 4) {
        int2 p0 = pair[k], p1 = pair[k + 1], p2 = pair[k + 2], p3 = pair[k + 3];
        float f0 = (float)h1b[(size_t)p0.x * 64 + j];
        float f1 = (float)h1b[(size_t)p1.x * 64 + j];
        float f2 = (float)h1b[(size_t)p2.x * 64 + j];
        float f3 = (float)h1b[(size_t)p3.x * 64 + j];
        acc += __int_as_float(p0.y) * f0; acc += __int_as_float(p1.y) * f1;
        acc += __int_as_float(p2.y) * f2; acc += __int_as_float(p3.y) * f3;
    }
    for (; k < r1; ++k) {
        int2 p = pair[k];
        acc += __int_as_float(p.y) * (float)h1b[(size_t)p.x * 64 + j];
    }
    acc *= inv;

    float x = (float)h1b[(size_t)node * 64 + j] * acc;
    bf16 xh = (bf16)x;
    bf16 xl = (bf16)(x - (float)xh);
    xsh[w][j] = xh;
    xsl[w][j] = xl;
    const int m16 = j & 15, q = j >> 4;
    bf16x8 ah0 = *(const bf16x8*)&xsh[w][q * 8];
    bf16x8 ah1 = *(const bf16x8*)&xsh[w][32 + q * 8];
    bf16x8 al0 = *(const bf16x8*)&xsl[w][q * 8];
    bf16x8 al1 = *(const bf16x8*)&xsl[w][32 + q * 8];

    float cand0, cand1;
#pragma unroll
    for (int nt = 0; nt < 2; ++nt) {
        const bf16* bh = W1Th + (nt * 16 + m16) * 64;
        const bf16* bl = W1Tl + (nt * 16 + m16) * 64;
        bf16x8 bh0 = *(const bf16x8*)(bh + q * 8);
        bf16x8 bh1 = *(const bf16x8*)(bh + 32 + q * 8);
        bf16x8 bl0 = *(const bf16x8*)(bl + q * 8);
        bf16x8 bl1 = *(const bf16x8*)(bl + 32 + q * 8);
        f32x4 c = {0.f, 0.f, 0.f, 0.f};
        c = __builtin_amdgcn_mfma_f32_16x16x32_bf16(ah0, bh0, c, 0, 0, 0);
        c = __builtin_amdgcn_mfma_f32_16x16x32_bf16(ah1, bh1, c, 0, 0, 0);
        c = __builtin_amdgcn_mfma_f32_16x16x32_bf16(al0, bh0, c, 0, 0, 0);
        c = __builtin_amdgcn_mfma_f32_16x16x32_bf16(al1, bh1, c, 0, 0, 0);
        c = __builtin_amdgcn_mfma_f32_16x16x32_bf16(ah0, bl0, c, 0, 0, 0);
        c = __builtin_amdgcn_mfma_f32_16x16x32_bf16(ah1, bl1, c, 0, 0, 0);
        float v = c[0];
        if (nt == 0) cand0 = v; else cand1 = v;
    }
    float a2 = ((q & 1) == 0) ? cand0 : cand1;   // lanes 32-63 duplicate 0-31 (harmless)

    float h2 = a2 > 0.f ? a2 : 0.01f * a2;
    float ss = h2 * h2;
#pragma unroll
    for (int o = 1; o < 32; o <<= 1) ss += __shfl_xor(ss, o);
    float inv3 = 1.f / fmaxf(sqrtf(ss), 1e-12f);
    if (j < 32) out[(size_t)node * OUT_STRIDE + 128 + j] = h2 * inv3;
}

extern "C" void kernel_launch(void* const* d_in, const int* in_sizes, int n_in,
                              void* d_out, int out_size, void* d_ws, size_t ws_size,
                              hipStream_t stream) {
    const float* ent = (const float*)d_in[0];
    const float* rel = (const float*)d_in[1];
    const float* W_R = (const float*)d_in[2];
    const float* W0  = (const float*)d_in[3];
    const float* W1  = (const float*)d_in[4];
    const int*   src = (const int*)d_in[5];
    const int*   dst = (const int*)d_in[6];
    const int*   ety = (const int*)d_in[7];
    float* out = (float*)d_out;

    char* ws = (char*)d_ws;
    size_t off = 0;
    auto take = [&](size_t bytes) -> char* {
        char* p = ws + off;
        off += (bytes + 255) & ~(size_t)255;
        return p;
    };
    int4*  bedge = (int4*)take((size_t)E_PAD * 16);       // 25.6 MB {src,dst,rank,0}; dead after fused_att
    bf16*  entb  = (bf16*)take((size_t)N_ENT * 64 * 2);   // 12.8 MB bf16 entity rows
    int2*  pair  = (int2*)take((size_t)N_EDGES * 8);      // 12.8 MB {src, exp(att)} in CSR order
    int*   cnt   = (int*)take((size_t)(2 * N_ENT + 16) * 4);  // cnt | cnt16 | denom (one fill)
    int*   cnt16 = cnt + N_ENT;
    float* denom = (float*)(cnt + N_ENT + 16);
    int*   rowp  = (int*)take((size_t)(N_ENT + 1) * 4);
    int*   part  = (int*)take(NCHUNK * 4);
    int*   pbase = (int*)take(NCHUNK * 4);
    int*   bptr16= (int*)take(68);
    int*   cur16 = (int*)take(64);
    bf16*  W0Th  = (bf16*)take(64 * 64 * 2);              // W0^T bf16 hi
    bf16*  W0Tl  = (bf16*)take(64 * 64 * 2);              // W0^T bf16 lo
    bf16*  W1Th  = (bf16*)take(32 * 64 * 2);              // W1^T bf16 hi
    bf16*  W1Tl  = (bf16*)take(32 * 64 * 2);              // W1^T bf16 lo
    size_t needed = off;                                   // ~52.7 MB
    // overlay: h1b (12.8) over bedge (25.6, dead after fused_att)
    bf16* h1b = (bf16*)bedge;

    if (needed > ws_size) {
        zero_out_kernel<<<512, 256, 0, stream>>>(out, out_size);
        return;
    }

    fill_kernel<<<512, 256, 0, stream>>>(cnt, 0, 2 * N_ENT + 16);   // cnt + cnt16 + denom(0.0f)
    ent2b_kernel<<<2048, 256, 0, stream>>>(ent, entb, W0, W1, W0Th, W0Tl, W1Th, W1Tl);

    hist16_kernel<<<N_EDGES / 256, 256, 0, stream>>>(ety, cnt16);
    bucket_scan<<<1, 64, 0, stream>>>(cnt16, bptr16, cur16);
    pad_fill<<<1, 256, 0, stream>>>(cnt16, bptr16, bedge);
    bucket_scatter<<<N_EDGES / 256, 256, 0, stream>>>(src, dst, ety, cur16, bedge, cnt);

    scan1<<<NCHUNK, 256, 0, stream>>>(cnt, part);
    scan2<<<1, 64, 0, stream>>>(part, pbase);
    scan3<<<NCHUNK, 256, 0, stream>>>(cnt, pbase, rowp);

    fused_att<<<dim3(128, N_REL), 256, 0, stream>>>(entb, W_R, rel, bedge, bptr16, rowp, pair, denom);

    fused_layer1<<<N_ENT / 4, 256, 0, stream>>>(ent, entb, W0Th, W0Tl, rowp, denom, pair, h1b, out);
    fused_layer2<<<N_ENT / 4, 256, 0, stream>>>(h1b, W1Th, W1Tl, rowp, denom, pair, out);
}

// Round 4
// 724.663 us; speedup vs baseline: 1.0139x; 1.0139x over previous
//
#include <hip/hip_runtime.h>
#include <hip/hip_bf16.h>
#include <math.h>

typedef __bf16 bf16;
typedef __bf16 bf16x8 __attribute__((ext_vector_type(8)));
typedef float f32x4 __attribute__((ext_vector_type(4)));

#define N_ENT   100000
#define N_REL   16
#define N_EDGES 1600000
#define E_PAD   (N_EDGES + 256)   // bucket records padded (<=16 pad slots per relation)
#define OUT_STRIDE 160
#define NCHUNK  98   // ceil(N_ENT/1024)

#define REP16(M) M(0) M(1) M(2) M(3) M(4) M(5) M(6) M(7) M(8) M(9) M(10) M(11) M(12) M(13) M(14) M(15)

// ---------- fill an int region (grid-stride) ----------
__global__ __launch_bounds__(256) void fill_kernel(int* __restrict__ p, int v, int n) {
    int i = blockIdx.x * 256 + threadIdx.x;
    int stride = gridDim.x * 256;
    for (; i < n; i += stride) p[i] = v;
}

// ---------- ws-too-small tripwire ----------
__global__ __launch_bounds__(256) void zero_out_kernel(float* __restrict__ out, int n) {
    int i = blockIdx.x * 256 + threadIdx.x;
    int stride = gridDim.x * 256;
    for (; i < n; i += stride) out[i] = 0.f;
}

// ---------- ent (fp32) -> entb (bf16) + out[:,0:64]=ent; builds W0^T / W1^T bf16 hi/lo ----------
__global__ __launch_bounds__(256) void ent2b_kernel(const float* __restrict__ ent, bf16* __restrict__ entb,
                                                    const float* __restrict__ W0, const float* __restrict__ W1,
                                                    bf16* __restrict__ W0Th, bf16* __restrict__ W0Tl,
                                                    bf16* __restrict__ W1Th, bf16* __restrict__ W1Tl,
                                                    float* __restrict__ out) {
    int id = blockIdx.x * 256 + threadIdx.x;
    if (id < 4096) {                 // W0 is [64][64] row-major: W0[k*64+n] -> W0T[n][k]
        int k = id >> 6, n = id & 63;
        float v = W0[id];
        bf16 h = (bf16)v;
        W0Th[n * 64 + k] = h;
        W0Tl[n * 64 + k] = (bf16)(v - (float)h);
        if (id < 2048) {             // W1 is [64][32]: W1[k*32+n] -> W1T[n][k]
            int k1 = id >> 5, n1 = id & 31;
            float v1 = W1[id];
            bf16 h1 = (bf16)v1;
            W1Th[n1 * 64 + k1] = h1;
            W1Tl[n1 * 64 + k1] = (bf16)(v1 - (float)h1);
        }
    }
    int i = id * 4;
    int stride = gridDim.x * 1024;
    for (; i < N_ENT * 64; i += stride) {
        float4 v = *(const float4*)(ent + i);
        entb[i]     = (bf16)v.x;
        entb[i + 1] = (bf16)v.y;
        entb[i + 2] = (bf16)v.z;
        entb[i + 3] = (bf16)v.w;
        int n = i >> 6, d = i & 63;
        *(float4*)(out + (size_t)n * OUT_STRIDE + d) = v;   // h0 copy (removed from layer1)
    }
}

// ---------- etype histogram (LDS-staged) ----------
__global__ __launch_bounds__(256) void hist16_kernel(const int* __restrict__ ety, int* __restrict__ cnt16) {
    __shared__ int h16[16];
    int t = threadIdx.x;
    if (t < 16) h16[t] = 0;
    __syncthreads();
    int e = blockIdx.x * 256 + t;
    if (e < N_EDGES) atomicAdd(&h16[ety[e]], 1);
    __syncthreads();
    if (t < 16 && h16[t] > 0) atomicAdd(&cnt16[t], h16[t]);
}

// padded bucket offsets (each bucket start multiple of 16)
__global__ void bucket_scan(const int* __restrict__ cnt16, int* __restrict__ bptr16, int* __restrict__ cur16) {
    if (threadIdx.x == 0) {
        int s = 0;
        for (int r = 0; r < N_REL; ++r) {
            bptr16[r] = s; cur16[r] = s;
            s += (cnt16[r] + 15) & ~15;
        }
        bptr16[N_REL] = s;
    }
}

// set dst=-1 sentinel on the <=16 pad slots at the tail of each relation bucket
__global__ void pad_fill(const int* __restrict__ cnt16, const int* __restrict__ bptr16, int4* __restrict__ bedge) {
    int t = threadIdx.x;           // 256 threads: r = t>>4, i = t&15
    int r = t >> 4, i = t & 15;
    int idx = bptr16[r] + cnt16[r] + i;
    if (idx < bptr16[r + 1]) bedge[idx] = make_int4(0, -1, 0, 0);
}

// ballot-rank scatter into padded etype buckets; record = {src, dst, within-dst rank, 0}
__global__ __launch_bounds__(256) void bucket_scatter(const int* __restrict__ src, const int* __restrict__ dst,
                                                      const int* __restrict__ ety, int* __restrict__ cur16,
                                                      int4* __restrict__ bedge, int* __restrict__ cnt) {
    __shared__ int whist[4][16];
    __shared__ int wbase[4][16];
    __shared__ int bbase[16];
    int t = threadIdx.x, wave = t >> 6, lane = t & 63;
    int e = blockIdx.x * 256 + t;
    int b = -1, d = 0, nrank = 0;
    if (e < N_EDGES) {
        b = ety[e];
        d = dst[e];
        nrank = atomicAdd(&cnt[d], 1);
    }
    unsigned long long ltmask = (1ull << lane) - 1ull;
    int brk = 0;
#pragma unroll
    for (int r = 0; r < 16; ++r) {
        unsigned long long mk = __ballot(b == r);
        if (b == r) brk = __popcll(mk & ltmask);
        if (lane == r) whist[wave][r] = __popcll(mk);
    }
    __syncthreads();
    if (t < 16) {
        int s0 = whist[0][t], s1 = whist[1][t], s2 = whist[2][t], s3 = whist[3][t];
        bbase[t] = atomicAdd(&cur16[t], s0 + s1 + s2 + s3);
        wbase[0][t] = 0; wbase[1][t] = s0; wbase[2][t] = s0 + s1; wbase[3][t] = s0 + s1 + s2;
    }
    __syncthreads();
    if (b >= 0) {
        int pos = bbase[b] + wbase[wave][b] + brk;
        bedge[pos] = make_int4(src[e], d, nrank, 0);
    }
}

// ---------- dst-CSR scans ----------
__global__ __launch_bounds__(256) void scan1(const int* __restrict__ cnt, int* __restrict__ part) {
    __shared__ int sh[256];
    int bIdx = blockIdx.x, t = threadIdx.x;
    int i0 = bIdx * 1024 + t * 4;
    int s = 0;
#pragma unroll
    for (int u = 0; u < 4; ++u) { int i = i0 + u; if (i < N_ENT) s += cnt[i]; }
    sh[t] = s; __syncthreads();
    for (int o = 128; o > 0; o >>= 1) { if (t < o) sh[t] += sh[t + o]; __syncthreads(); }
    if (t == 0) part[bIdx] = sh[0];
}

__global__ void scan2(const int* __restrict__ part, int* __restrict__ pbase) {
    if (threadIdx.x == 0) {
        int s = 0;
        for (int i = 0; i < NCHUNK; ++i) { pbase[i] = s; s += part[i]; }
    }
}

__global__ __launch_bounds__(256) void scan3(const int* __restrict__ cnt, const int* __restrict__ pbase,
                                             int* __restrict__ row_ptr) {
    __shared__ int sh[256];
    int bIdx = blockIdx.x, t = threadIdx.x;
    int i0 = bIdx * 1024 + t * 4;
    int c[4]; int s = 0;
#pragma unroll
    for (int u = 0; u < 4; ++u) { c[u] = (i0 + u < N_ENT) ? cnt[i0 + u] : 0; s += c[u]; }
    sh[t] = s; __syncthreads();
    for (int o = 1; o < 256; o <<= 1) {
        int add = (t >= o) ? sh[t - o] : 0;
        __syncthreads();
        sh[t] += add;
        __syncthreads();
    }
    int run = pbase[bIdx] + sh[t] - s;
#pragma unroll
    for (int u = 0; u < 4; ++u) {
        if (i0 + u < N_ENT) { row_ptr[i0 + u] = run; run += c[u]; }
    }
    if (bIdx == 0 && t == 0) row_ptr[N_ENT] = N_EDGES;
}

// ---------- fused per-edge MFMA attention ----------
// Writes pair[rowp[d]+rank] = {src, exp(att)}. No max-subtraction needed (|att| is O(1) for
// this data scale) and no denominator pass: layer kernels sum pair.y inline.
__global__ __launch_bounds__(256) void fused_att(const bf16* __restrict__ entb, const float* __restrict__ W_R,
                                                 const float* __restrict__ rel, const int4* __restrict__ bedge,
                                                 const int* __restrict__ bptr16, const int* __restrict__ rowp,
                                                 int2* __restrict__ pair) {
    __shared__ bf16 WT[64 * 72];     // WT[n][k] = W_r[k][n]
    __shared__ float relS[64];
    const int r = blockIdx.y;
    const int t = threadIdx.x;
    const float* Wr = W_R + (size_t)r * 4096;
    for (int idx = t; idx < 4096; idx += 256) {
        int k = idx >> 6, n = idx & 63;
        WT[n * 72 + k] = (bf16)Wr[idx];
    }
    if (t < 64) relS[t] = rel[r * 64 + t];
    __syncthreads();

    const int lane = t & 63, m = lane & 15, q = lane >> 4;
    bf16x8 bb[4][2];
#pragma unroll
    for (int nt = 0; nt < 4; ++nt)
#pragma unroll
        for (int ks = 0; ks < 2; ++ks)
            bb[nt][ks] = *(const bf16x8*)&WT[(nt * 16 + m) * 72 + ks * 32 + q * 8];

    int g0 = bptr16[r] >> 4, g1 = bptr16[r + 1] >> 4;
    int wv = blockIdx.x * 4 + (t >> 6);
    int nw = gridDim.x * 4;
    for (int g = g0 + wv; g < g1; g += nw) {
        int4 be = bedge[g * 16 + m];
        int sidx = be.x < 0 ? 0 : be.x;      // pad slots clamped for the gather
        int didx = be.y < 0 ? 0 : be.y;
        const bf16* sp = entb + (size_t)sidx * 64;
        const bf16* dp = entb + (size_t)didx * 64;
        bf16x8 as0 = *(const bf16x8*)(sp + q * 8);
        bf16x8 as1 = *(const bf16x8*)(sp + 32 + q * 8);
        bf16x8 ad0 = *(const bf16x8*)(dp + q * 8);
        bf16x8 ad1 = *(const bf16x8*)(dp + 32 + q * 8);
        float part0 = 0.f, part1 = 0.f, part2 = 0.f, part3 = 0.f;
#pragma unroll
        for (int nt = 0; nt < 4; ++nt) {
            f32x4 tacc = {0.f, 0.f, 0.f, 0.f};
            tacc = __builtin_amdgcn_mfma_f32_16x16x32_bf16(as0, bb[nt][0], tacc, 0, 0, 0);
            tacc = __builtin_amdgcn_mfma_f32_16x16x32_bf16(as1, bb[nt][1], tacc, 0, 0, 0);
            f32x4 hacc = {0.f, 0.f, 0.f, 0.f};
            hacc = __builtin_amdgcn_mfma_f32_16x16x32_bf16(ad0, bb[nt][0], hacc, 0, 0, 0);
            hacc = __builtin_amdgcn_mfma_f32_16x16x32_bf16(ad1, bb[nt][1], hacc, 0, 0, 0);
            float rl = relS[nt * 16 + m];
#pragma unroll
            for (int i = 0; i < 4; ++i) {
                float z = hacc[i] + rl;
                float ez = __expf(2.f * z);                 // tanh(z) = 1 - 2/(e^{2z}+1)
                float th = 1.f - 2.f / (ez + 1.f);
                float tv = tacc[i] * th;
                if (i == 0) part0 += tv; else if (i == 1) part1 += tv;
                else if (i == 2) part2 += tv; else part3 += tv;
            }
        }
#pragma unroll
        for (int o = 1; o < 16; o <<= 1) {    // reduce over dim-lanes; xor<16 stays in edge group
            part0 += __shfl_xor(part0, o);
            part1 += __shfl_xor(part1, o);
            part2 += __shfl_xor(part2, o);
            part3 += __shfl_xor(part3, o);
        }
        if (m == 0) {
            float v[4] = {part0, part1, part2, part3};
#pragma unroll
            for (int i = 0; i < 4; ++i) {
                int4 w = bedge[g * 16 + q * 4 + i];          // L1-hot reread
                if (w.y >= 0) {
                    int slot = rowp[w.y] + w.z;              // unique CSR slot, no atomic
                    pair[slot] = make_int2(w.x, __float_as_int(__expf(v[i])));
                }
            }
        }
    }
}

// ---------- 16-wide batched CSR gather: issue all pair loads, then all row loads ----------
// Single two-level latency chain for deg<=16 (the common case); clamped masked batch for the
// remainder (no serial narrow tail). All names static (registers, not scratch).
// dsum accumulates the softmax denominator (= sum of pair.y over the row) as a side effect.
__device__ __forceinline__ void gather16(const int2* __restrict__ pair, const bf16* __restrict__ tab,
                                         int r0, int r1, int j, float& acc, float& dsum) {
    int k = r0;
    for (; k + 16 <= r1; k += 16) {
#define LDP(u) int2 p##u = pair[k + u];
        REP16(LDP)
#undef LDP
#define LDR(u) float f##u = (float)tab[(size_t)p##u.x * 64 + j];
        REP16(LDR)
#undef LDR
#define ACCW(u) { float w_ = __int_as_float(p##u.y); dsum += w_; acc += w_ * f##u; }
        REP16(ACCW)
#undef ACCW
    }
    if (k < r1) {
        int last = r1 - 1;
#define LDPM(u) int e##u = k + u; if (e##u > last) e##u = last; int2 p##u = pair[e##u];
        REP16(LDPM)
#undef LDPM
#define LDRM(u) float f##u = (float)tab[(size_t)p##u.x * 64 + j];
        REP16(LDRM)
#undef LDRM
#define ACCM(u) { float w_ = (k + u <= last) ? __int_as_float(p##u.y) : 0.f; dsum += w_; acc += w_ * f##u; }
        REP16(ACCM)
#undef ACCM
    }
}

// ---------- fused layer 1: batched gather + inline denom + MFMA transform1 ----------
__global__ __launch_bounds__(256) void fused_layer1(const float* __restrict__ ent, const bf16* __restrict__ entb,
                                                    const bf16* __restrict__ W0Th, const bf16* __restrict__ W0Tl,
                                                    const int* __restrict__ rowp,
                                                    const int2* __restrict__ pair, bf16* __restrict__ h1b,
                                                    float* __restrict__ out) {
    __shared__ bf16 xsh[4][80];   // per-wave x hi strip
    __shared__ bf16 xsl[4][80];   // per-wave x lo strip
    int t = threadIdx.x;
    int w = t >> 6;
    int node = blockIdx.x * 4 + w;           // grid is exactly N_ENT/4
    int j = t & 63;
    float h0v = ent[(size_t)node * 64 + j];  // issue early, consumed late
    int r0 = __builtin_amdgcn_readfirstlane(rowp[node]);
    int r1 = __builtin_amdgcn_readfirstlane(rowp[node + 1]);

    float acc = 0.f, dsum = 0.f;
    if (r0 < r1) {
        gather16(pair, entb, r0, r1, j, acc, dsum);
        acc *= 1.f / dsum;                   // deg>0 -> dsum>0 (sum of exp)
    }

    // transform1: h1 = lrelu((h0 * agg) @ W0) via MFMA, bf16 hi/lo split (~fp32 accuracy)
    float x = h0v * acc;
    bf16 xh = (bf16)x;
    bf16 xl = (bf16)(x - (float)xh);
    xsh[w][j] = xh;
    xsl[w][j] = xl;
    // same-wave LDS RAW: compiler inserts lgkmcnt; no __syncthreads (waves independent)
    const int m16 = j & 15, q = j >> 4;
    bf16x8 ah0 = *(const bf16x8*)&xsh[w][q * 8];        // row-replicated A fragments
    bf16x8 ah1 = *(const bf16x8*)&xsh[w][32 + q * 8];
    bf16x8 al0 = *(const bf16x8*)&xsl[w][q * 8];
    bf16x8 al1 = *(const bf16x8*)&xsl[w][32 + q * 8];

    float cand0, cand1, cand2, cand3;
#pragma unroll
    for (int nt = 0; nt < 4; ++nt) {
        const bf16* bh = W0Th + (nt * 16 + m16) * 64;   // B[col=nt*16+m16][k]
        const bf16* bl = W0Tl + (nt * 16 + m16) * 64;
        bf16x8 bh0 = *(const bf16x8*)(bh + q * 8);
        bf16x8 bh1 = *(const bf16x8*)(bh + 32 + q * 8);
        bf16x8 bl0 = *(const bf16x8*)(bl + q * 8);
        bf16x8 bl1 = *(const bf16x8*)(bl + 32 + q * 8);
        f32x4 c = {0.f, 0.f, 0.f, 0.f};
        c = __builtin_amdgcn_mfma_f32_16x16x32_bf16(ah0, bh0, c, 0, 0, 0);
        c = __builtin_amdgcn_mfma_f32_16x16x32_bf16(ah1, bh1, c, 0, 0, 0);
        c = __builtin_amdgcn_mfma_f32_16x16x32_bf16(al0, bh0, c, 0, 0, 0);
        c = __builtin_amdgcn_mfma_f32_16x16x32_bf16(al1, bh1, c, 0, 0, 0);
        c = __builtin_amdgcn_mfma_f32_16x16x32_bf16(ah0, bl0, c, 0, 0, 0);
        c = __builtin_amdgcn_mfma_f32_16x16x32_bf16(ah1, bl1, c, 0, 0, 0);
        // all C rows identical (A rows replicated) -> c[0] = out[col=m16] of block nt
        float v = c[0];
        if (nt == 0) cand0 = v; else if (nt == 1) cand1 = v; else if (nt == 2) cand2 = v; else cand3 = v;
    }
    // lane j (= q*16 + m16) already holds outdim j in cand_q
    float a2 = (q == 0) ? cand0 : (q == 1) ? cand1 : (q == 2) ? cand2 : cand3;

    float h1v = a2 > 0.f ? a2 : 0.01f * a2;
    h1b[(size_t)node * 64 + j] = (bf16)h1v;
    float ss = h1v * h1v;
#pragma unroll
    for (int o = 1; o < 64; o <<= 1) ss += __shfl_xor(ss, o);
    float inv2 = 1.f / fmaxf(sqrtf(ss), 1e-12f);
    out[(size_t)node * OUT_STRIDE + 64 + j] = h1v * inv2;
}

// ---------- fused layer 2: batched gather (h1b rows) + inline denom + MFMA transform2 ----------
__global__ __launch_bounds__(256) void fused_layer2(const bf16* __restrict__ h1b,
                                                    const bf16* __restrict__ W1Th, const bf16* __restrict__ W1Tl,
                                                    const int* __restrict__ rowp,
                                                    const int2* __restrict__ pair, float* __restrict__ out) {
    __shared__ bf16 xsh[4][80];
    __shared__ bf16 xsl[4][80];
    int t = threadIdx.x;
    int w = t >> 6;
    int node = blockIdx.x * 4 + w;
    int j = t & 63;
    float h1self = (float)h1b[(size_t)node * 64 + j];   // issue early
    int r0 = __builtin_amdgcn_readfirstlane(rowp[node]);
    int r1 = __builtin_amdgcn_readfirstlane(rowp[node + 1]);

    float acc = 0.f, dsum = 0.f;
    if (r0 < r1) {
        gather16(pair, h1b, r0, r1, j, acc, dsum);
        acc *= 1.f / dsum;
    }

    float x = h1self * acc;
    bf16 xh = (bf16)x;
    bf16 xl = (bf16)(x - (float)xh);
    xsh[w][j] = xh;
    xsl[w][j] = xl;
    const int m16 = j & 15, q = j >> 4;
    bf16x8 ah0 = *(const bf16x8*)&xsh[w][q * 8];
    bf16x8 ah1 = *(const bf16x8*)&xsh[w][32 + q * 8];
    bf16x8 al0 = *(const bf16x8*)&xsl[w][q * 8];
    bf16x8 al1 = *(const bf16x8*)&xsl[w][32 + q * 8];

    float cand0, cand1;
#pragma unroll
    for (int nt = 0; nt < 2; ++nt) {
        const bf16* bh = W1Th + (nt * 16 + m16) * 64;
        const bf16* bl = W1Tl + (nt * 16 + m16) * 64;
        bf16x8 bh0 = *(const bf16x8*)(bh + q * 8);
        bf16x8 bh1 = *(const bf16x8*)(bh + 32 + q * 8);
        bf16x8 bl0 = *(const bf16x8*)(bl + q * 8);
        bf16x8 bl1 = *(const bf16x8*)(bl + 32 + q * 8);
        f32x4 c = {0.f, 0.f, 0.f, 0.f};
        c = __builtin_amdgcn_mfma_f32_16x16x32_bf16(ah0, bh0, c, 0, 0, 0);
        c = __builtin_amdgcn_mfma_f32_16x16x32_bf16(ah1, bh1, c, 0, 0, 0);
        c = __builtin_amdgcn_mfma_f32_16x16x32_bf16(al0, bh0, c, 0, 0, 0);
        c = __builtin_amdgcn_mfma_f32_16x16x32_bf16(al1, bh1, c, 0, 0, 0);
        c = __builtin_amdgcn_mfma_f32_16x16x32_bf16(ah0, bl0, c, 0, 0, 0);
        c = __builtin_amdgcn_mfma_f32_16x16x32_bf16(ah1, bl1, c, 0, 0, 0);
        float v = c[0];
        if (nt == 0) cand0 = v; else cand1 = v;
    }
    float a2 = ((q & 1) == 0) ? cand0 : cand1;   // lanes 32-63 duplicate 0-31 (harmless)

    float h2 = a2 > 0.f ? a2 : 0.01f * a2;
    float ss = h2 * h2;
#pragma unroll
    for (int o = 1; o < 32; o <<= 1) ss += __shfl_xor(ss, o);
    float inv3 = 1.f / fmaxf(sqrtf(ss), 1e-12f);
    if (j < 32) out[(size_t)node * OUT_STRIDE + 128 + j] = h2 * inv3;
}

extern "C" void kernel_launch(void* const* d_in, const int* in_sizes, int n_in,
                              void* d_out, int out_size, void* d_ws, size_t ws_size,
                              hipStream_t stream) {
    const float* ent = (const float*)d_in[0];
    const float* rel = (const float*)d_in[1];
    const float* W_R = (const float*)d_in[2];
    const float* W0  = (const float*)d_in[3];
    const float* W1  = (const float*)d_in[4];
    const int*   src = (const int*)d_in[5];
    const int*   dst = (const int*)d_in[6];
    const int*   ety = (const int*)d_in[7];
    float* out = (float*)d_out;

    char* ws = (char*)d_ws;
    size_t off = 0;
    auto take = [&](size_t bytes) -> char* {
        char* p = ws + off;
        off += (bytes + 255) & ~(size_t)255;
        return p;
    };
    int4*  bedge = (int4*)take((size_t)E_PAD * 16);       // 25.6 MB {src,dst,rank,0}; dead after fused_att
    bf16*  entb  = (bf16*)take((size_t)N_ENT * 64 * 2);   // 12.8 MB bf16 entity rows
    int2*  pair  = (int2*)take((size_t)N_EDGES * 8);      // 12.8 MB {src, exp(att)} in CSR order
    int*   cnt   = (int*)take((size_t)(N_ENT + 16) * 4);  // cnt16 = cnt+N_ENT
    int*   cnt16 = cnt + N_ENT;
    int*   rowp  = (int*)take((size_t)(N_ENT + 1) * 4);
    int*   part  = (int*)take(NCHUNK * 4);
    int*   pbase = (int*)take(NCHUNK * 4);
    int*   bptr16= (int*)take(68);
    int*   cur16 = (int*)take(64);
    bf16*  W0Th  = (bf16*)take(64 * 64 * 2);              // W0^T bf16 hi
    bf16*  W0Tl  = (bf16*)take(64 * 64 * 2);              // W0^T bf16 lo
    bf16*  W1Th  = (bf16*)take(32 * 64 * 2);              // W1^T bf16 hi
    bf16*  W1Tl  = (bf16*)take(32 * 64 * 2);              // W1^T bf16 lo
    size_t needed = off;                                   // ~52.3 MB
    // overlay: h1b (12.8) over bedge (25.6, dead after fused_att)
    bf16* h1b = (bf16*)bedge;

    if (needed > ws_size) {
        zero_out_kernel<<<512, 256, 0, stream>>>(out, out_size);
        return;
    }

    fill_kernel<<<512, 256, 0, stream>>>(cnt, 0, N_ENT + 16);
    ent2b_kernel<<<2048, 256, 0, stream>>>(ent, entb, W0, W1, W0Th, W0Tl, W1Th, W1Tl, out);

    hist16_kernel<<<N_EDGES / 256, 256, 0, stream>>>(ety, cnt16);
    bucket_scan<<<1, 64, 0, stream>>>(cnt16, bptr16, cur16);
    pad_fill<<<1, 256, 0, stream>>>(cnt16, bptr16, bedge);
    bucket_scatter<<<N_EDGES / 256, 256, 0, stream>>>(src, dst, ety, cur16, bedge, cnt);

    scan1<<<NCHUNK, 256, 0, stream>>>(cnt, part);
    scan2<<<1, 64, 0, stream>>>(part, pbase);
    scan3<<<NCHUNK, 256, 0, stream>>>(cnt, pbase, rowp);

    fused_att<<<dim3(128, N_REL), 256, 0, stream>>>(entb, W_R, rel, bedge, bptr16, rowp, pair);

    fused_layer1<<<N_ENT / 4, 256, 0, stream>>>(ent, entb, W0Th, W0Tl, rowp, pair, h1b, out);
    fused_layer2<<<N_ENT / 4, 256, 0, stream>>>(h1b, W1Th, W1Tl, rowp, pair, out);
}